// Round 5
// baseline (154.164 us; speedup 1.0000x reference)
//
#include <hip/hip_runtime.h>

#define B 4
#define C 128
#define H 128
#define W 128
#define HW (H * W)
#define KK 9
#define MID 25

#define SPATIAL_BLKS (HW / 64)   // 256 spatial blocks per batch

// Workspace layout (floats):
//   [0, 512)           xm      (unused now)
//   [1024, 5632)       ch      (B*C*KK) channel filter
//   [8192, 598016)     S       (B*KK*HW) spatial filter
//   [600064, 731136)   part    (B*SPATIAL_BLKS*C) per-block channel sums
#define WS_CH   1024
#define WS_S    8192
#define WS_PART 600064

// K1: fused spatial filter + per-block channel partial sums.
// grid (SPATIAL_BLKS, B), block 256 = 4 waves; wave w handles channels
// [32w, 32w+32) for 64 pixels. The per-channel pixel sums (for the mean)
// are butterfly-reduced from the SAME registers the spatial dot product
// already loaded — x is read exactly once by this kernel.
__global__ __launch_bounds__(256) void k_ms(
    const float* __restrict__ x, const float* __restrict__ Ws,
    const float* __restrict__ bs, float* __restrict__ part,
    float* __restrict__ S)
{
    __shared__ float red[3 * KK * 64];
    const int b = blockIdx.y;
    const int lane = threadIdx.x & 63;
    const int wave = threadIdx.x >> 6;
    const int p = blockIdx.x * 64 + lane;
    const float* xb = x + (size_t)b * C * HW + p;

    float acc[KK];
#pragma unroll
    for (int k = 0; k < KK; ++k) acc[k] = (wave == 0) ? bs[k] : 0.0f;

    const int cbase = wave * 32;
    float msum = 0.0f;   // lane i keeps channel cbase+i's pixel-sum
#pragma unroll
    for (int i = 0; i < 32; ++i) {
        const int c = cbase + i;                 // wave-uniform -> scalar Ws loads
        float v = xb[(size_t)c * HW];
#pragma unroll
        for (int k = 0; k < KK; ++k)
            acc[k] = fmaf(v, Ws[k * C + c], acc[k]);
        // butterfly: every lane ends with the 64-pixel sum for channel c
        float s = v;
#pragma unroll
        for (int m = 1; m <= 32; m <<= 1) s += __shfl_xor(s, m, 64);
        msum = (lane == i) ? s : msum;
    }
    if (lane < 32)   // one coalesced 128B store of 32 channel partials per wave
        part[((size_t)b * SPATIAL_BLKS + blockIdx.x) * C + cbase + lane] = msum;

    if (wave > 0) {
#pragma unroll
        for (int k = 0; k < KK; ++k)
            red[((wave - 1) * KK + k) * 64 + lane] = acc[k];
    }
    __syncthreads();
    if (wave == 0) {
#pragma unroll
        for (int k = 0; k < KK; ++k) {
            float a = acc[k] + red[(0 * KK + k) * 64 + lane]
                             + red[(1 * KK + k) * 64 + lane]
                             + red[(2 * KK + k) * 64 + lane];
            S[((size_t)(b * KK + k)) * HW + p] = 1.0f / (1.0f + __expf(-a));
        }
    }
}

// K2: partial-sum reduce + channel MLP. grid 18 blocks x 256 threads; each
// block redundantly reduces the 512KB partials (L2-resident) and computes
// hid, then 256 of the 4608 ch outputs.
__global__ __launch_bounds__(256) void k_mlp(
    const float* __restrict__ part, const float* __restrict__ W1,
    const float* __restrict__ b1, const float* __restrict__ W2,
    const float* __restrict__ b2, float* __restrict__ ch)
{
    __shared__ float xmean[B * C];
    __shared__ float hid[B * MID];
    const int tid = threadIdx.x;

    for (int i = tid; i < B * C; i += 256) {
        const int b = i >> 7, c = i & (C - 1);
        const float* pp = part + (size_t)b * SPATIAL_BLKS * C + c;
        float s = 0.0f;
#pragma unroll 8
        for (int blk = 0; blk < SPATIAL_BLKS; ++blk)
            s += pp[(size_t)blk * C];            // coalesced across threads
        xmean[i] = s * (1.0f / HW);
    }
    __syncthreads();

    if (tid < B * MID) {
        const int b = tid / MID, m = tid % MID;
        float a = b1[m];
#pragma unroll 8
        for (int c = 0; c < C; ++c)
            a = fmaf(xmean[b * C + c], W1[m * C + c], a);
        hid[tid] = fmaxf(a, 0.0f);
    }
    __syncthreads();

    const int idx = blockIdx.x * 256 + tid;   // 18*256 == B*C*KK == 4608
    const int b = idx / (C * KK);
    const int o = idx % (C * KK);
    float a = b2[o];
#pragma unroll
    for (int m = 0; m < MID; ++m)
        a = fmaf(hid[b * MID + m], W2[o * MID + m], a);
    ch[idx] = 1.0f / (1.0f + __expf(-a));
}

// K3: dynamic 3x3 conv, float4-vectorized: each thread owns 4 consecutive
// pixels of one row. grid (16 z-chunks [fastest], B, HW/1024); z fastest so
// the 16 blocks sharing one S region / x halo are dispatch-adjacent
// (round-robin over the 8 XCDs -> L2 reuse instead of 16x HBM re-fetch).
__global__ __launch_bounds__(256) void k_conv(
    const float* __restrict__ x, const float* __restrict__ S,
    const float* __restrict__ ch, float* __restrict__ out)
{
    const int tid = threadIdx.x;
    const int b = blockIdx.y;
    const int p0 = (blockIdx.z * 256 + tid) * 4;
    const int h = p0 >> 7;          // /W
    const int w0 = p0 & (W - 1);    // multiple of 4

    // 9 per-pixel spatial-filter vectors; fold row/col tap validity into them.
    float4 sv[KK];
    const float* Sb = S + (size_t)b * KK * HW + p0;
#pragma unroll
    for (int k = 0; k < KK; ++k) {
        const int di = k / 3 - 1, dj = k % 3 - 1;
        const int hh = h + di;
        float4 s4 = *(const float4*)(Sb + (size_t)k * HW);
        if (hh < 0 || hh >= H) s4 = make_float4(0.f, 0.f, 0.f, 0.f);
        if (dj == -1 && w0 == 0)     s4.x = 0.f;   // col -1
        if (dj == +1 && w0 == W - 4) s4.w = 0.f;   // col W
        sv[k] = s4;
    }

    const int r0 = max(h - 1, 0), r2 = min(h + 1, H - 1);
    const int rowoff[3] = { r0 * W + w0, h * W + w0, r2 * W + w0 };
    const int loff = (w0 > 0) ? -1 : 0;       // masked by sv when w0==0
    const int roff = (w0 < W - 4) ? 4 : 0;    // masked by sv when w0==W-4

    const int c0 = blockIdx.x * (C / 16);
    const float* xb = x + (size_t)b * C * HW;
    const float* chb = ch + b * C * KK;
    float* ob = out + (size_t)b * C * HW + p0;

    for (int c = c0; c < c0 + C / 16; ++c) {
        const float* xc = xb + (size_t)c * HW;
        float4 Cx[3];
        float  Lw[3], Rx[3];
#pragma unroll
        for (int r = 0; r < 3; ++r) {
            const float* bp = xc + rowoff[r];
            Cx[r] = *(const float4*)bp;
            Lw[r] = bp[loff];
            Rx[r] = bp[roff];
        }
        float4 a = make_float4(0.f, 0.f, 0.f, 0.f);
#pragma unroll
        for (int k = 0; k < KK; ++k) {
            const int r = k / 3, dj = k % 3 - 1;
            float4 t;
            if (dj == -1)     t = make_float4(Lw[r], Cx[r].x, Cx[r].y, Cx[r].z);
            else if (dj == 0) t = Cx[r];
            else              t = make_float4(Cx[r].y, Cx[r].z, Cx[r].w, Rx[r]);
            const float cf = chb[c * KK + k];   // uniform -> scalar load
            a.x = fmaf(t.x, sv[k].x * cf, a.x);
            a.y = fmaf(t.y, sv[k].y * cf, a.y);
            a.z = fmaf(t.z, sv[k].z * cf, a.z);
            a.w = fmaf(t.w, sv[k].w * cf, a.w);
        }
        *(float4*)(ob + (size_t)c * HW) = a;    // coalesced 16B store
    }
}

extern "C" void kernel_launch(void* const* d_in, const int* in_sizes, int n_in,
                              void* d_out, int out_size, void* d_ws, size_t ws_size,
                              hipStream_t stream) {
    (void)in_sizes; (void)n_in; (void)out_size; (void)ws_size;
    const float* x  = (const float*)d_in[0];
    const float* Ws = (const float*)d_in[1];
    const float* bs = (const float*)d_in[2];
    const float* W1 = (const float*)d_in[3];
    const float* b1 = (const float*)d_in[4];
    const float* W2 = (const float*)d_in[5];
    const float* b2 = (const float*)d_in[6];
    float* out = (float*)d_out;
    float* ws  = (float*)d_ws;

    float* ch   = ws + WS_CH;
    float* S    = ws + WS_S;
    float* part = ws + WS_PART;

    k_ms<<<dim3(SPATIAL_BLKS, B), 256, 0, stream>>>(x, Ws, bs, part, S);
    k_mlp<<<18, 256, 0, stream>>>(part, W1, b1, W2, b2, ch);
    k_conv<<<dim3(16, B, HW / 1024), 256, 0, stream>>>(x, S, ch, out);
}

// Round 6
// 123.230 us; speedup vs baseline: 1.2510x; 1.2510x over previous
//
#include <hip/hip_runtime.h>

#define B 4
#define C 128
#define H 128
#define W 128
#define HW (H * W)
#define KK 9
#define MID 25

#define SPATIAL_BLKS (HW / 64)   // 256 spatial blocks per batch

// Workspace layout (floats):
//   [0, 512)        xm      (B*C)   per-channel means
//   [8192, 598016)  S       (B*KK*HW) spatial filter
#define WS_XM 0
#define WS_S  8192

// K1: block-specialized fused kernel. grid (SPATIAL_BLKS + C, B), block 256.
//  - blocks [0, SPATIAL_BLKS): spatial filter sigmoid(x . Ws + bs).
//    4 waves split channels (32 each), fully unrolled, LDS cross-wave reduce.
//  - blocks [SPATIAL_BLKS, SPATIAL_BLKS+C): per-(b,c)-plane mean.
//  (R5's in-loop butterfly mean was a ~27us regression: 192 dependent DS-pipe
//   ops per wave serialized the hot loop. The overlapped x re-read is cheaper.)
__global__ __launch_bounds__(256) void k_ms(
    const float* __restrict__ x, const float* __restrict__ Ws,
    const float* __restrict__ bs, float* __restrict__ xm,
    float* __restrict__ S)
{
    __shared__ float red[3 * KK * 64];
    const int b = blockIdx.y;

    if (blockIdx.x >= SPATIAL_BLKS) {
        // ---- mean path ----
        const int c = blockIdx.x - SPATIAL_BLKS;
        const float4* plane = (const float4*)(x + ((size_t)b * C + c) * HW);
        float s = 0.0f;
#pragma unroll
        for (int i = 0; i < 16; ++i) {
            float4 v = plane[i * 256 + threadIdx.x];
            s += (v.x + v.y) + (v.z + v.w);
        }
#pragma unroll
        for (int off = 32; off > 0; off >>= 1) s += __shfl_down(s, off, 64);
        if ((threadIdx.x & 63) == 0) red[threadIdx.x >> 6] = s;
        __syncthreads();
        if (threadIdx.x == 0)
            xm[b * C + c] = ((red[0] + red[1]) + (red[2] + red[3])) * (1.0f / HW);
        return;
    }

    // ---- spatial path ----
    const int lane = threadIdx.x & 63;
    const int wave = threadIdx.x >> 6;
    const int p = blockIdx.x * 64 + lane;
    const float* xb = x + (size_t)b * C * HW + p;

    float acc[KK];
#pragma unroll
    for (int k = 0; k < KK; ++k) acc[k] = (wave == 0) ? bs[k] : 0.0f;

    const int cbase = wave * 32;
#pragma unroll
    for (int i = 0; i < 32; ++i) {
        const int c = cbase + i;                 // wave-uniform -> scalar Ws loads
        float v = xb[(size_t)c * HW];
#pragma unroll
        for (int k = 0; k < KK; ++k)
            acc[k] = fmaf(v, Ws[k * C + c], acc[k]);
    }

    if (wave > 0) {
#pragma unroll
        for (int k = 0; k < KK; ++k)
            red[((wave - 1) * KK + k) * 64 + lane] = acc[k];
    }
    __syncthreads();
    if (wave == 0) {
#pragma unroll
        for (int k = 0; k < KK; ++k) {
            float a = acc[k] + red[(0 * KK + k) * 64 + lane]
                             + red[(1 * KK + k) * 64 + lane]
                             + red[(2 * KK + k) * 64 + lane];
            S[((size_t)(b * KK + k)) * HW + p] = 1.0f / (1.0f + __expf(-a));
        }
    }
}

// K3: dynamic 3x3 conv with fused channel-MLP preamble (k_mlp dispatch removed).
// Each block redundantly computes hid[b,:] (3.2 KFLOP) and its own 72 ch
// values from xm; W1/W2 are L2-hot. Then the float4 conv: each thread owns
// 4 consecutive pixels. grid (HW/1024, B, 16) — pixel-block fastest (R4
// ordering: the 16 S-sharers are 64 apart = same XCD -> L2 reuse).
__global__ __launch_bounds__(256) void k_conv(
    const float* __restrict__ x, const float* __restrict__ S,
    const float* __restrict__ xm,
    const float* __restrict__ W1, const float* __restrict__ b1,
    const float* __restrict__ W2, const float* __restrict__ b2,
    float* __restrict__ out)
{
    const int tid = threadIdx.x;
    const int b = blockIdx.y;
    const int c0 = blockIdx.z * (C / 16);

    // ---- MLP preamble: ch[c0..c0+8) x 9 into LDS ----
    __shared__ float xmean[C];
    __shared__ float hid[MID];
    __shared__ float chs[(C / 16) * KK];   // 72
    if (tid < C) xmean[tid] = xm[b * C + tid];
    __syncthreads();
    if (tid < MID) {
        float a = b1[tid];
#pragma unroll 8
        for (int c = 0; c < C; ++c)
            a = fmaf(xmean[c], W1[tid * C + c], a);
        hid[tid] = fmaxf(a, 0.0f);
    }
    __syncthreads();
    if (tid < (C / 16) * KK) {
        const int o = c0 * KK + tid;
        float a = b2[o];
#pragma unroll
        for (int m = 0; m < MID; ++m)
            a = fmaf(hid[m], W2[o * MID + m], a);
        chs[tid] = 1.0f / (1.0f + __expf(-a));
    }
    __syncthreads();

    // ---- conv ----
    const int p0 = (blockIdx.x * 256 + tid) * 4;
    const int h = p0 >> 7;          // /W
    const int w0 = p0 & (W - 1);    // multiple of 4

    // 9 per-pixel spatial-filter vectors; fold row/col tap validity into them.
    float4 sv[KK];
    const float* Sb = S + (size_t)b * KK * HW + p0;
#pragma unroll
    for (int k = 0; k < KK; ++k) {
        const int di = k / 3 - 1, dj = k % 3 - 1;
        const int hh = h + di;
        float4 s4 = *(const float4*)(Sb + (size_t)k * HW);
        if (hh < 0 || hh >= H) s4 = make_float4(0.f, 0.f, 0.f, 0.f);
        if (dj == -1 && w0 == 0)     s4.x = 0.f;   // col -1
        if (dj == +1 && w0 == W - 4) s4.w = 0.f;   // col W
        sv[k] = s4;
    }

    const int r0 = max(h - 1, 0), r2 = min(h + 1, H - 1);
    const int rowoff[3] = { r0 * W + w0, h * W + w0, r2 * W + w0 };
    const int loff = (w0 > 0) ? -1 : 0;       // masked by sv when w0==0
    const int roff = (w0 < W - 4) ? 4 : 0;    // masked by sv when w0==W-4

    const float* xb = x + (size_t)b * C * HW;
    float* ob = out + (size_t)b * C * HW + p0;

    for (int ci = 0; ci < C / 16; ++ci) {
        const int c = c0 + ci;
        const float* xc = xb + (size_t)c * HW;
        float4 Cx[3];
        float  Lw[3], Rx[3];
#pragma unroll
        for (int r = 0; r < 3; ++r) {
            const float* bp = xc + rowoff[r];
            Cx[r] = *(const float4*)bp;
            Lw[r] = bp[loff];
            Rx[r] = bp[roff];
        }
        float4 a = make_float4(0.f, 0.f, 0.f, 0.f);
#pragma unroll
        for (int k = 0; k < KK; ++k) {
            const int r = k / 3, dj = k % 3 - 1;
            float4 t;
            if (dj == -1)     t = make_float4(Lw[r], Cx[r].x, Cx[r].y, Cx[r].z);
            else if (dj == 0) t = Cx[r];
            else              t = make_float4(Cx[r].y, Cx[r].z, Cx[r].w, Rx[r]);
            const float cf = chs[ci * KK + k];  // uniform -> LDS broadcast
            a.x = fmaf(t.x, sv[k].x * cf, a.x);
            a.y = fmaf(t.y, sv[k].y * cf, a.y);
            a.z = fmaf(t.z, sv[k].z * cf, a.z);
            a.w = fmaf(t.w, sv[k].w * cf, a.w);
        }
        *(float4*)(ob + (size_t)c * HW) = a;    // coalesced 16B store
    }
}

extern "C" void kernel_launch(void* const* d_in, const int* in_sizes, int n_in,
                              void* d_out, int out_size, void* d_ws, size_t ws_size,
                              hipStream_t stream) {
    (void)in_sizes; (void)n_in; (void)out_size; (void)ws_size;
    const float* x  = (const float*)d_in[0];
    const float* Ws = (const float*)d_in[1];
    const float* bs = (const float*)d_in[2];
    const float* W1 = (const float*)d_in[3];
    const float* b1 = (const float*)d_in[4];
    const float* W2 = (const float*)d_in[5];
    const float* b2 = (const float*)d_in[6];
    float* out = (float*)d_out;
    float* ws  = (float*)d_ws;

    float* xm = ws + WS_XM;
    float* S  = ws + WS_S;

    k_ms<<<dim3(SPATIAL_BLKS + C, B), 256, 0, stream>>>(x, Ws, bs, xm, S);
    k_conv<<<dim3(HW / 1024, B, 16), 256, 0, stream>>>(x, S, xm, W1, b1, W2, b2, out);
}